// Round 12
// baseline (186.301 us; speedup 1.0000x reference)
//
#include <hip/hip_runtime.h>

typedef _Float16 half8 __attribute__((ext_vector_type(8)));
typedef _Float16 half4_t __attribute__((ext_vector_type(4)));
typedef float f32x4 __attribute__((ext_vector_type(4)));

#define MFMA(a, b, c) __builtin_amdgcn_mfma_f32_16x16x32_f16(a, b, c, 0, 0, 0)

constexpr int T_TOK = 4096;
constexpr int DMODEL = 1024;
constexpr int WLOC = 256;

typedef const __attribute__((address_space(1))) uint32_t* gptr_t;
typedef __attribute__((address_space(3))) uint32_t* lptr_t;
static __device__ __forceinline__ void gl16(const void* g, void* l) {
  __builtin_amdgcn_global_load_lds((gptr_t)g, (lptr_t)l, 16, 0, 0);
}

// ---------- fused cast f32->f16 + gate ----------
__global__ __launch_bounds__(256) void k_castgate(const float* __restrict__ hs,
                                                  const float* __restrict__ Wg,
                                                  const float* __restrict__ bg,
                                                  _Float16* __restrict__ out,
                                                  float* __restrict__ gate) {
  int w = threadIdx.x >> 6, lane = threadIdx.x & 63;
  int t = blockIdx.x * 4 + w;
  const float* row = hs + (size_t)t * DMODEL;
  _Float16* orow = out + (size_t)t * DMODEL;
  float s = 0.f;
#pragma unroll
  for (int i = 0; i < 4; ++i) {
    int off = lane * 4 + i * 256;
    f32x4 v = *(const f32x4*)(row + off);
    f32x4 g = *(const f32x4*)(Wg + off);
    s += v[0] * g[0] + v[1] * g[1] + v[2] * g[2] + v[3] * g[3];
    half4_t h;
    h[0] = (_Float16)v[0]; h[1] = (_Float16)v[1];
    h[2] = (_Float16)v[2]; h[3] = (_Float16)v[3];
    *(half4_t*)(orow + off) = h;
  }
#pragma unroll
  for (int off = 32; off; off >>= 1) s += __shfl_xor(s, off);
  if (lane == 0) gate[t] = 1.f / (1.f + __expf(-(s + bg[0])));
}

// ---------- transpose + cast: f32 [R][C] -> f16 [C][R] ----------
__global__ __launch_bounds__(256) void k_transpose_cast(const float* __restrict__ in,
                                                        _Float16* __restrict__ out,
                                                        int R, int C) {
  __shared__ float tile[64][65];
  int r0 = blockIdx.y * 64, c0 = blockIdx.x * 64;
  int tr = threadIdx.x >> 4;
  int tc = (threadIdx.x & 15) * 4;
#pragma unroll
  for (int p = 0; p < 4; ++p) {
    int r = p * 16 + tr;
    f32x4 v = *(const f32x4*)&in[(size_t)(r0 + r) * C + c0 + tc];
    tile[r][tc + 0] = v[0]; tile[r][tc + 1] = v[1];
    tile[r][tc + 2] = v[2]; tile[r][tc + 3] = v[3];
  }
  __syncthreads();
#pragma unroll
  for (int p = 0; p < 4; ++p) {
    int c = p * 16 + tr;
    half4_t h;
    h[0] = (_Float16)tile[tc + 0][c];
    h[1] = (_Float16)tile[tc + 1][c];
    h[2] = (_Float16)tile[tc + 2][c];
    h[3] = (_Float16)tile[tc + 3][c];
    *(half4_t*)&out[(size_t)(c0 + c) * R + r0 + tc] = h;
  }
}

// ---------- f16 MFMA GEMM: 3-buffer, 2-ahead prefetch, counted vmcnt (T3+T4) ----------
// Invariant: before barrier_t every wave has waited vmcnt(4) => step-(t+1)'s loads
// (4 newest-but-one group) landed chip-wide; buf[(t+2)%3] WAR-safe because its
// step-(t-1) readers consumed into regs before barrier_{t-1}. vmcnt never 0 in loop.
template <int MODE, int NBX>
__global__ __launch_bounds__(256) void k_gemm(const _Float16* __restrict__ A,
                                              const _Float16* __restrict__ Bt,
                                              const float* __restrict__ bias,
                                              float* __restrict__ Cout,
                                              _Float16* __restrict__ qh,
                                              _Float16* __restrict__ kh,
                                              _Float16* __restrict__ vt,
                                              int M, int N, int K) {
  __shared__ __align__(16) _Float16 As[3][128][32];   // 3 x 8 KB
  __shared__ __align__(16) _Float16 Bs[3][128][32];
  int nwg = gridDim.x;
  int cpx = nwg >> 3;
  int orig = blockIdx.x;
  int wg = (orig & 7) * cpx + (orig >> 3);   // bijective XCD swizzle (nwg%8==0)
  int bx = wg % NBX, by = wg / NBX;
  int m0 = by * 128, n0 = bx * 128;

  int tid = threadIdx.x;
  int lane = tid & 63, wave = tid >> 6;
  int wm = wave >> 1, wn = wave & 1;
  int lr = lane & 15, lk = (lane >> 4) * 8;
  int sr = tid >> 2, sc = (tid & 3) * 8;
  f32x4 acc[4][4] = {};

  auto stage = [&](int kt, int b) {
    gl16(&A[(size_t)(m0 + sr) * K + kt + sc],       &As[b][sr][sc]);
    gl16(&A[(size_t)(m0 + sr + 64) * K + kt + sc],  &As[b][sr + 64][sc]);
    gl16(&Bt[(size_t)(n0 + sr) * K + kt + sc],      &Bs[b][sr][sc]);
    gl16(&Bt[(size_t)(n0 + sr + 64) * K + kt + sc], &Bs[b][sr + 64][sc]);
  };

  int T = K >> 5;
  stage(0, 0);
  stage(32, 1);
  asm volatile("s_waitcnt vmcnt(4)" ::: "memory");   // step-0 loads landed
  __builtin_amdgcn_s_barrier();

  for (int t = 0; t < T; ++t) {
    int b = t % 3;
    bool more = (t + 2 < T);
    if (more) stage((t + 2) << 5, (t + 2) % 3);      // issue 2-ahead FIRST
    half8 af[4], bf[4];
#pragma unroll
    for (int i = 0; i < 4; ++i) af[i] = *(half8*)&As[b][wm * 64 + i * 16 + lr][lk];
#pragma unroll
    for (int i = 0; i < 4; ++i) bf[i] = *(half8*)&Bs[b][wn * 64 + i * 16 + lr][lk];
#pragma unroll
    for (int i = 0; i < 4; ++i)
#pragma unroll
      for (int j = 0; j < 4; ++j)
        acc[i][j] = MFMA(af[i], bf[j], acc[i][j]);
    if (more) asm volatile("s_waitcnt vmcnt(4)" ::: "memory");  // (t+1) landed, (t+2) flies
    else      asm volatile("s_waitcnt vmcnt(0)" ::: "memory");  // tail drain
    __builtin_amdgcn_s_barrier();
  }

  int lg2 = lane >> 4;
#pragma unroll
  for (int j = 0; j < 4; ++j) {
    int n = n0 + wn * 64 + j * 16 + lr;
    float b = bias[n];
#pragma unroll
    for (int i = 0; i < 4; ++i) {
      int mm0 = m0 + wm * 64 + i * 16 + lg2 * 4;
      if (MODE == 1) {
#pragma unroll
        for (int r = 0; r < 4; ++r)
          Cout[(size_t)(mm0 + r) * N + n] = acc[i][j][r] + b;
      } else {
        int hh = (n >> 6) & 15, d = n & 63;
        if (n < 2048) {
          _Float16* dst = (n < 1024) ? qh : kh;
#pragma unroll
          for (int r = 0; r < 4; ++r)
            dst[((size_t)hh * T_TOK + mm0 + r) * 64 + d] = (_Float16)(acc[i][j][r] + b);
        } else {
          half4_t v4;   // vT: m contiguous -> vectorized 8B store
#pragma unroll
          for (int r = 0; r < 4; ++r) v4[r] = (_Float16)(acc[i][j][r] + b);
          *(half4_t*)&vt[((size_t)hh * 64 + d) * T_TOK + mm0] = v4;
        }
      }
    }
  }
}

// ---------- fused attention v3 (unchanged) ----------
__global__ __launch_bounds__(256) void k_attn(const _Float16* __restrict__ q_all,
                                              const _Float16* __restrict__ k_all,
                                              const _Float16* __restrict__ vT_all,
                                              const float* __restrict__ gate,
                                              _Float16* __restrict__ attn_h) {
  __shared__ __align__(16) _Float16 Ks[64][72];
  __shared__ __align__(16) _Float16 Vs[64][72];
  __shared__ __align__(16) _Float16 P[4][16][72];

  int n = blockIdx.x;
  int o = (n & 7) * 128 + (n >> 3);
  int h = o >> 6, qb = o & 63;
  int q0 = qb * 64;
  int tid = threadIdx.x;
  int lane = tid & 63, w = tid >> 6;
  int lr = lane & 15, lgp = lane >> 4;

  const _Float16* qh = q_all + (size_t)h * T_TOK * 64;
  const _Float16* kh = k_all + (size_t)h * T_TOK * 64;
  const _Float16* vt = vT_all + (size_t)h * 64 * T_TOK;

  half8 aq0 = *(const half8*)&qh[(size_t)(q0 + w * 16 + lr) * 64 + lgp * 8];
  half8 aq1 = *(const half8*)&qh[(size_t)(q0 + w * 16 + lr) * 64 + 32 + lgp * 8];
#pragma unroll
  for (int j = 0; j < 8; ++j) { aq0[j] = aq0[j] * (_Float16)0.125f; aq1[j] = aq1[j] * (_Float16)0.125f; }

  int r8 = tid >> 3, c8 = (tid & 7) * 8;
  half8 kr0, kr1, vr0, vr1;

  auto ldregs = [&](int key0) {
    kr0 = *(const half8*)&kh[(size_t)(key0 + r8) * 64 + c8];
    kr1 = *(const half8*)&kh[(size_t)(key0 + r8 + 32) * 64 + c8];
    vr0 = *(const half8*)&vt[(size_t)r8 * T_TOK + key0 + c8];
    vr1 = *(const half8*)&vt[(size_t)(r8 + 32) * T_TOK + key0 + c8];
  };
  auto dswrite = [&]() {
    *(half8*)&Ks[r8][c8]      = kr0;
    *(half8*)&Ks[r8 + 32][c8] = kr1;
    *(half8*)&Vs[r8][c8]      = vr0;
    *(half8*)&Vs[r8 + 32][c8] = vr1;
  };

  f32x4 acc_g[4] = {}, acc_l[4] = {};
  float m_g = -1e30f, l_g = 0.f, m_l = -1e30f, l_l = 0.f;

  auto compute = [&](int key0, bool use_mask, f32x4 (&acc)[4], float& ms, float& ls) {
    f32x4 s[4] = {};
#pragma unroll
    for (int g = 0; g < 4; ++g) {
      half8 b0 = *(half8*)&Ks[g * 16 + lr][lgp * 8];
      half8 b1 = *(half8*)&Ks[g * 16 + lr][32 + lgp * 8];
      s[g] = MFMA(b0, aq0, s[g]);
      s[g] = MFMA(b1, aq1, s[g]);
    }
    if (use_mask) {
      int moff = key0 + lgp * 4 - (q0 + w * 16 + lr) + WLOC;
#pragma unroll
      for (int g = 0; g < 4; ++g)
#pragma unroll
        for (int r = 0; r < 4; ++r) {
          unsigned u = (unsigned)(moff + g * 16 + r);
          if (u > 2u * WLOC) s[g][r] = -1e30f;
        }
    }
    float mloc = -1e30f;
#pragma unroll
    for (int g = 0; g < 4; ++g)
#pragma unroll
      for (int r = 0; r < 4; ++r) mloc = fmaxf(mloc, s[g][r]);
    mloc = fmaxf(mloc, __shfl_xor(mloc, 16));
    mloc = fmaxf(mloc, __shfl_xor(mloc, 32));
    if (__any(mloc > ms)) {
      float mn = fmaxf(ms, mloc);
      float al = __expf(ms - mn);
      ms = mn;
      float alr[4];
#pragma unroll
      for (int r = 0; r < 4; ++r) alr[r] = __shfl(al, lgp * 4 + r);
#pragma unroll
      for (int dt = 0; dt < 4; ++dt)
#pragma unroll
        for (int r = 0; r < 4; ++r) acc[dt][r] *= alr[r];
      ls *= al;
    }
    float rsum = 0.f;
#pragma unroll
    for (int g = 0; g < 4; ++g)
#pragma unroll
      for (int r = 0; r < 4; ++r) {
        float p = __expf(s[g][r] - ms);
        s[g][r] = p;
        rsum += p;
      }
    rsum += __shfl_xor(rsum, 16);
    rsum += __shfl_xor(rsum, 32);
    ls += rsum;
#pragma unroll
    for (int g = 0; g < 4; ++g) {
      half4_t q4;
      q4[0] = (_Float16)s[g][0]; q4[1] = (_Float16)s[g][1];
      q4[2] = (_Float16)s[g][2]; q4[3] = (_Float16)s[g][3];
      *(half4_t*)&P[w][lr][g * 16 + lgp * 4] = q4;
    }
    half8 pa0 = *(half8*)&P[w][lr][lgp * 8];
    half8 pa1 = *(half8*)&P[w][lr][32 + lgp * 8];
#pragma unroll
    for (int dt = 0; dt < 4; ++dt) {
      half8 bv0 = *(half8*)&Vs[dt * 16 + lr][lgp * 8];
      half8 bv1 = *(half8*)&Vs[dt * 16 + lr][32 + lgp * 8];
      acc[dt] = MFMA(pa0, bv0, acc[dt]);
      acc[dt] = MFMA(pa1, bv1, acc[dt]);
    }
  };

  ldregs(0);
  dswrite();
  __syncthreads();
  int lo = q0 - WLOC; if (lo < 0) lo = 0;
  int hi = q0 + 63 + WLOC + 1; if (hi > T_TOK) hi = T_TOK;
  ldregs(lo);
  compute(0, false, acc_g, m_g, l_g);
  __syncthreads();
  dswrite();
  __syncthreads();

  for (int key0 = lo; key0 < hi; key0 += 64) {
    int nxt = key0 + 64;
    bool have_nxt = nxt < hi;
    if (have_nxt) ldregs(nxt);
    bool use_mask = (key0 < q0 - 192) || (key0 > q0 + 192);
    compute(key0, use_mask, acc_l, m_l, l_l);
    __syncthreads();
    if (have_nxt) { dswrite(); __syncthreads(); }
  }

  float llr[4], lgr[4];
#pragma unroll
  for (int r = 0; r < 4; ++r) {
    llr[r] = __shfl(l_l, lgp * 4 + r);
    lgr[r] = __shfl(l_g, lgp * 4 + r);
  }
#pragma unroll
  for (int r = 0; r < 4; ++r) {
    int q = q0 + w * 16 + lgp * 4 + r;
    float g = gate[q];
#pragma unroll
    for (int dt = 0; dt < 4; ++dt) {
      float o2 = (1.f - g) * (acc_l[dt][r] / llr[r]) + g * (acc_g[dt][r] / lgr[r]);
      attn_h[(size_t)q * DMODEL + h * 64 + dt * 16 + lr] = (_Float16)o2;
    }
  }
}

extern "C" void kernel_launch(void* const* d_in, const int* in_sizes, int n_in,
                              void* d_out, int out_size, void* d_ws, size_t ws_size,
                              hipStream_t stream) {
  const float* hs   = (const float*)d_in[0];
  const float* Wqkv = (const float*)d_in[1];
  const float* bqkv = (const float*)d_in[2];
  const float* Wout = (const float*)d_in[3];
  const float* bout = (const float*)d_in[4];
  const float* Wg   = (const float*)d_in[5];
  const float* bg   = (const float*)d_in[6];
  float* out = (float*)d_out;

  char* ws = (char*)d_ws;
  _Float16* hidden_h = (_Float16*)(ws);               // 8 MB
  _Float16* Wqkv_t   = (_Float16*)(ws + 8388608);     // 6 MB
  _Float16* Wout_t   = (_Float16*)(ws + 14680064);    // 2 MB
  _Float16* q_h      = (_Float16*)(ws + 16777216);    // 8 MB
  _Float16* k_h      = (_Float16*)(ws + 25165824);    // 8 MB
  _Float16* vT_h     = (_Float16*)(ws + 33554432);    // 8 MB
  float*    gate     = (float*)(ws + 41943040);       // 16 KB
  _Float16* attn_h   = hidden_h;  // reuse: hidden_h dead after QKV GEMM

  k_castgate<<<1024, 256, 0, stream>>>(hs, Wg, bg, hidden_h, gate);
  k_transpose_cast<<<dim3(48, 16), 256, 0, stream>>>(Wqkv, Wqkv_t, 1024, 3072);
  k_transpose_cast<<<dim3(16, 16), 256, 0, stream>>>(Wout, Wout_t, 1024, 1024);
  k_gemm<0, 24><<<768, 256, 0, stream>>>(hidden_h, Wqkv_t, bqkv, nullptr,
                                         q_h, k_h, vT_h, 4096, 3072, 1024);
  k_attn<<<1024, 256, 0, stream>>>(q_h, k_h, vT_h, gate, attn_h);
  k_gemm<1, 8><<<256, 256, 0, stream>>>(attn_h, Wout_t, bout, out,
                                        nullptr, nullptr, nullptr, 4096, 1024, 1024);
}